// Round 2
// baseline (582.638 us; speedup 1.0000x reference)
//
#include <hip/hip_runtime.h>
#include <math.h>

#define Bq 8
#define Sq 4096
#define Hq 4096
#define NHq 32
#define KVHq 8
#define HDq 128
#define QKV_N 6144   // NH*HD + 2*KVH*HD
#define CHUNK 128
#define NCHUNK 32    // S / CHUNK
#define ROWS 128     // split-K row chunk for gemv

// y[b*ldY + col] += sum_r x[b*K + r] * W[r*ldW + col]  over rows [blockIdx.y*ROWS, +ROWS)
// 16-deep row unroll: 16 independent 4B loads in flight per thread (64B) for HBM latency hiding.
__global__ __launch_bounds__(256, 4) void gemv_splitk(
    const float* __restrict__ x, const float* __restrict__ W,
    float* __restrict__ y, int K, int ldW, int ldY) {
  __shared__ float xs[Bq][ROWS];
  int tid = threadIdx.x;
  int r0 = blockIdx.y * ROWS;
  for (int i = tid; i < Bq * ROWS; i += 256) {
    int b = i >> 7, r = i & (ROWS - 1);
    xs[b][r] = x[b * K + r0 + r];
  }
  __syncthreads();
  int col = blockIdx.x * 256 + tid;
  float acc[Bq] = {0, 0, 0, 0, 0, 0, 0, 0};
  const float* wp = W + (size_t)r0 * ldW + col;
  for (int r = 0; r < ROWS; r += 16) {
    float w[16];
#pragma unroll
    for (int i = 0; i < 16; i++) w[i] = wp[(size_t)(r + i) * ldW];
#pragma unroll
    for (int i = 0; i < 16; i++) {
#pragma unroll
      for (int b = 0; b < Bq; b++)
        acc[b] = fmaf(xs[b][r + i], w[i], acc[b]);
    }
  }
#pragma unroll
  for (int b = 0; b < Bq; b++) atomicAdd(&y[b * ldY + col], acc[b]);
}

// One wave per vector: 256 q vectors (rmsnorm+rope -> qvec), 64 k vectors
// (rmsnorm+rope -> key_cache[step]), 64 v vectors (copy -> value_cache[step]).
__global__ __launch_bounds__(256) void normrope(
    const float* __restrict__ qkv, const float* __restrict__ cosp,
    const float* __restrict__ sinp, const float* __restrict__ qnw,
    const float* __restrict__ knw, const int* __restrict__ step_ptr,
    float* __restrict__ kcache, float* __restrict__ vcache,
    float* __restrict__ qvec) {
  int tid = threadIdx.x;
  int lane = tid & 63, wid = tid >> 6;
  int vec = blockIdx.x * 4 + wid;  // 0..383
  int step = *step_ptr;
  if (vec < 256) {  // q heads
    int b = vec >> 5, h = vec & 31;
    const float* src = qkv + b * QKV_N + h * HDq;
    float x0 = src[lane], x1 = src[lane + 64];
    float ss = fmaf(x0, x0, x1 * x1);
#pragma unroll
    for (int off = 32; off; off >>= 1) ss += __shfl_xor(ss, off, 64);
    float sc = rsqrtf(ss * (1.0f / HDq) + 1e-6f);
    float n0 = x0 * sc * qnw[lane], n1 = x1 * sc * qnw[lane + 64];
    float c0 = cosp[b * HDq + lane], c1 = cosp[b * HDq + lane + 64];
    float s0 = sinp[b * HDq + lane], s1 = sinp[b * HDq + lane + 64];
    float* dst = qvec + b * (NHq * HDq) + h * HDq;
    dst[lane] = fmaf(n0, c0, -n1 * s0);
    dst[lane + 64] = fmaf(n1, c1, n0 * s1);
  } else if (vec < 320) {  // k heads
    int v = vec - 256;
    int b = v >> 3, kvh = v & 7;
    const float* src = qkv + b * QKV_N + NHq * HDq + kvh * HDq;
    float x0 = src[lane], x1 = src[lane + 64];
    float ss = fmaf(x0, x0, x1 * x1);
#pragma unroll
    for (int off = 32; off; off >>= 1) ss += __shfl_xor(ss, off, 64);
    float sc = rsqrtf(ss * (1.0f / HDq) + 1e-6f);
    float n0 = x0 * sc * knw[lane], n1 = x1 * sc * knw[lane + 64];
    float c0 = cosp[b * HDq + lane], c1 = cosp[b * HDq + lane + 64];
    float s0 = sinp[b * HDq + lane], s1 = sinp[b * HDq + lane + 64];
    float* dst = kcache + (((size_t)(b * KVHq + kvh)) * Sq + step) * HDq;
    dst[lane] = fmaf(n0, c0, -n1 * s0);
    dst[lane + 64] = fmaf(n1, c1, n0 * s1);
  } else {  // v heads
    int v = vec - 320;
    int b = v >> 3, kvh = v & 7;
    const float* src = qkv + b * QKV_N + (NHq + KVHq) * HDq + kvh * HDq;
    float* dst = vcache + (((size_t)(b * KVHq + kvh)) * Sq + step) * HDq;
    dst[lane] = src[lane];
    dst[lane + 64] = src[lane + 64];
  }
}

// Flash-decode partial: grid (NCHUNK, B*KVH). 128-thread blocks, 4 GQA heads x 128 positions.
__global__ __launch_bounds__(128, 4) void attn_partial(
    const float* __restrict__ qvec, const float* __restrict__ kc,
    const float* __restrict__ vc, const int* __restrict__ step_ptr,
    float* __restrict__ pm, float* __restrict__ pl, float* __restrict__ po) {
  int c = blockIdx.x;
  int bk = blockIdx.y;  // b*KVH + kvh
  int b = bk >> 3, kvh = bk & 7;
  int step = *step_ptr;
  int base = c * CHUNK;
  int pidx = (bk * NCHUNK + c) * 4;
  int tid = threadIdx.x;
  if (base > step) {
    if (tid < 4) { pm[pidx + tid] = -1e38f; pl[pidx + tid] = 0.0f; }
    return;
  }
  __shared__ float qs[4][HDq];
  __shared__ float pls[4][CHUNK];
  __shared__ float redm[4][2];
  __shared__ float redl[4][2];
  for (int i = tid; i < 4 * HDq; i += 128)
    qs[i >> 7][i & 127] = qvec[b * (NHq * HDq) + (kvh * 4 + (i >> 7)) * HDq + (i & 127)];
  __syncthreads();

  int s = base + tid;  // one position per thread
  const float* krow = kc + (((size_t)bk) * Sq + s) * HDq;
  float sc[4] = {0, 0, 0, 0};
#pragma unroll
  for (int d = 0; d < HDq; d += 4) {
    float4 kk = *(const float4*)(krow + d);
#pragma unroll
    for (int g = 0; g < 4; g++) {
      float4 qq = *(const float4*)&qs[g][d];
      sc[g] += kk.x * qq.x + kk.y * qq.y + kk.z * qq.z + kk.w * qq.w;
    }
  }
  const float scaling = 0.08838834764831845f;  // 1/sqrt(128)
  bool valid = (s <= step);
#pragma unroll
  for (int g = 0; g < 4; g++) sc[g] = valid ? sc[g] * scaling : -1e30f;

  int lane = tid & 63, wid = tid >> 6;
#pragma unroll
  for (int g = 0; g < 4; g++) {
    float v = sc[g];
#pragma unroll
    for (int off = 32; off; off >>= 1) v = fmaxf(v, __shfl_xor(v, off, 64));
    if (lane == 0) redm[g][wid] = v;
  }
  __syncthreads();
  float m[4];
#pragma unroll
  for (int g = 0; g < 4; g++) m[g] = fmaxf(redm[g][0], redm[g][1]);
#pragma unroll
  for (int g = 0; g < 4; g++) {
    float p = __expf(sc[g] - m[g]);  // invalid lanes underflow to 0
    pls[g][tid] = p;
    float v = p;
#pragma unroll
    for (int off = 32; off; off >>= 1) v += __shfl_xor(v, off, 64);
    if (lane == 0) redl[g][wid] = v;
  }
  __syncthreads();
  if (tid < 4) {
    pm[pidx + tid] = m[tid];
    pl[pidx + tid] = redl[tid][0] + redl[tid][1];
  }
  // o_c[g][d] = sum_s p[g][s] * V[s][d]; thread = d
  const float* vbase = vc + (((size_t)bk) * Sq + base) * HDq + tid;
  float o0 = 0.0f, o1 = 0.0f, o2 = 0.0f, o3 = 0.0f;
#pragma unroll 8
  for (int ss = 0; ss < CHUNK; ss++) {
    float vv = vbase[(size_t)ss * HDq];
    o0 = fmaf(pls[0][ss], vv, o0);
    o1 = fmaf(pls[1][ss], vv, o1);
    o2 = fmaf(pls[2][ss], vv, o2);
    o3 = fmaf(pls[3][ss], vv, o3);
  }
  po[(size_t)(pidx + 0) * HDq + tid] = o0;
  po[(size_t)(pidx + 1) * HDq + tid] = o1;
  po[(size_t)(pidx + 2) * HDq + tid] = o2;
  po[(size_t)(pidx + 3) * HDq + tid] = o3;
}

__global__ __launch_bounds__(128) void attn_combine(
    const float* __restrict__ pm, const float* __restrict__ pl,
    const float* __restrict__ po, float* __restrict__ aout) {
  int bh = blockIdx.x;  // 0..255
  int b = bh >> 5, h = bh & 31;
  int kvh = h >> 2, g = h & 3;
  int d = threadIdx.x;
  int bk = b * KVHq + kvh;
  float mv[NCHUNK];
  float M = -1e38f;
#pragma unroll
  for (int c = 0; c < NCHUNK; c++) {
    mv[c] = pm[(bk * NCHUNK + c) * 4 + g];
    M = fmaxf(M, mv[c]);
  }
  float L = 0.0f, o = 0.0f;
#pragma unroll
  for (int c = 0; c < NCHUNK; c++) {
    if (mv[c] > -1e37f) {
      float w = __expf(mv[c] - M);
      L = fmaf(pl[(bk * NCHUNK + c) * 4 + g], w, L);
      o = fmaf(po[(size_t)((bk * NCHUNK + c) * 4 + g) * HDq + d], w, o);
    }
  }
  aout[b * (NHq * HDq) + h * HDq + d] = o / L;
}

extern "C" void kernel_launch(void* const* d_in, const int* in_sizes, int n_in,
                              void* d_out, int out_size, void* d_ws, size_t ws_size,
                              hipStream_t stream) {
  const float* hidden = (const float*)d_in[0];
  const float* cosp   = (const float*)d_in[1];
  const float* sinp   = (const float*)d_in[2];
  float* kcache       = (float*)d_in[3];
  float* vcache       = (float*)d_in[4];
  // d_in[5] causal_mask unused (mask == skip s > step; masked exp underflows to 0)
  const float* q_w    = (const float*)d_in[6];
  const float* k_w    = (const float*)d_in[7];
  const float* v_w    = (const float*)d_in[8];
  const float* o_w    = (const float*)d_in[9];
  const float* qnw    = (const float*)d_in[10];
  const float* knw    = (const float*)d_in[11];
  const int* step_ptr = (const int*)d_in[12];
  float* out = (float*)d_out;
  float* ws = (float*)d_ws;

  float* qkv  = ws;            // 8*6144 = 49152
  float* qvec = ws + 49152;    // 8*32*128 = 32768
  float* aout = ws + 81920;    // 32768
  float* pm   = ws + 114688;   // 64*32*4 = 8192
  float* pl   = ws + 122880;   // 8192
  float* po   = ws + 131072;   // 64*32*4*128 = 1048576
  (void)in_sizes; (void)n_in; (void)ws_size;

  (void)hipMemsetAsync(qkv, 0, 49152 * sizeof(float), stream);
  (void)hipMemsetAsync(out, 0, (size_t)out_size * sizeof(float), stream);

  // QKV projections (split along columns of the fused weight)
  gemv_splitk<<<dim3(16, Hq / ROWS), 256, 0, stream>>>(hidden, q_w, qkv, Hq, 4096, QKV_N);
  gemv_splitk<<<dim3(4, Hq / ROWS), 256, 0, stream>>>(hidden, k_w, qkv + 4096, Hq, 1024, QKV_N);
  gemv_splitk<<<dim3(4, Hq / ROWS), 256, 0, stream>>>(hidden, v_w, qkv + 5120, Hq, 1024, QKV_N);

  normrope<<<96, 256, 0, stream>>>(qkv, cosp, sinp, qnw, knw, step_ptr, kcache, vcache, qvec);

  attn_partial<<<dim3(NCHUNK, Bq * KVHq), 128, 0, stream>>>(qvec, kcache, vcache, step_ptr, pm, pl, po);
  attn_combine<<<Bq * NHq, 128, 0, stream>>>(pm, pl, po, aout);

  // Output projection
  gemv_splitk<<<dim3(16, Hq / ROWS), 256, 0, stream>>>(aout, o_w, out, NHq * HDq, 4096, 4096);
}

// Round 3
// 555.470 us; speedup vs baseline: 1.0489x; 1.0489x over previous
//
#include <hip/hip_runtime.h>
#include <math.h>

#define Bq 8
#define Sq 4096
#define Hq 4096
#define NHq 32
#define KVHq 8
#define HDq 128
#define QKV_N 6144   // NH*HD + 2*KVH*HD
#define CHUNK 128
#define NCHUNK 32    // S / CHUNK
#define GROWS 64     // split-K rows per gemv block
#define NSPLIT 64    // 4096 / GROWS

// Fused QKV projection. grid (6, NSPLIT), block 256.
// Block covers 1024 virtual cols (4/thread) x GROWS rows; writes partials.
__global__ __launch_bounds__(256, 2) void qkv_gemv(
    const float* __restrict__ x, const float* __restrict__ q_w,
    const float* __restrict__ k_w, const float* __restrict__ v_w,
    float* __restrict__ part) {
  __shared__ float xs[Bq][GROWS];
  int tid = threadIdx.x;
  int sp = blockIdx.y;
  int r0 = sp * GROWS;
  for (int i = tid; i < Bq * GROWS; i += 256) {
    int b = i >> 6, r = i & (GROWS - 1);
    xs[b][r] = x[b * Hq + r0 + r];
  }
  __syncthreads();
  int cbase = blockIdx.x << 10;
  const float* W; int ldW; int cloc;
  if (cbase < 4096)      { W = q_w; ldW = 4096; cloc = cbase; }
  else if (cbase < 5120) { W = k_w; ldW = 1024; cloc = cbase - 4096; }
  else                   { W = v_w; ldW = 1024; cloc = cbase - 5120; }
  const float* wp = W + (size_t)r0 * ldW + cloc + 4 * tid;
  float4 acc[Bq];
#pragma unroll
  for (int b = 0; b < Bq; b++) acc[b] = make_float4(0.f, 0.f, 0.f, 0.f);
  for (int r = 0; r < GROWS; r += 8) {
    float4 w[8];
#pragma unroll
    for (int i = 0; i < 8; i++) w[i] = *(const float4*)(wp + (size_t)(r + i) * ldW);
#pragma unroll
    for (int i = 0; i < 8; i++) {
#pragma unroll
      for (int b = 0; b < Bq; b++) {
        float xv = xs[b][r + i];
        acc[b].x = fmaf(xv, w[i].x, acc[b].x);
        acc[b].y = fmaf(xv, w[i].y, acc[b].y);
        acc[b].z = fmaf(xv, w[i].z, acc[b].z);
        acc[b].w = fmaf(xv, w[i].w, acc[b].w);
      }
    }
  }
#pragma unroll
  for (int b = 0; b < Bq; b++)
    *(float4*)&part[((size_t)sp * Bq + b) * QKV_N + cbase + 4 * tid] = acc[b];
}

// O-projection. grid (4, NSPLIT), block 256. Same structure, single weight.
__global__ __launch_bounds__(256, 2) void o_gemv(
    const float* __restrict__ x, const float* __restrict__ W,
    float* __restrict__ part) {
  __shared__ float xs[Bq][GROWS];
  int tid = threadIdx.x;
  int sp = blockIdx.y;
  int r0 = sp * GROWS;
  for (int i = tid; i < Bq * GROWS; i += 256) {
    int b = i >> 6, r = i & (GROWS - 1);
    xs[b][r] = x[b * 4096 + r0 + r];
  }
  __syncthreads();
  int cbase = blockIdx.x << 10;
  const float* wp = W + (size_t)r0 * 4096 + cbase + 4 * tid;
  float4 acc[Bq];
#pragma unroll
  for (int b = 0; b < Bq; b++) acc[b] = make_float4(0.f, 0.f, 0.f, 0.f);
  for (int r = 0; r < GROWS; r += 8) {
    float4 w[8];
#pragma unroll
    for (int i = 0; i < 8; i++) w[i] = *(const float4*)(wp + (size_t)(r + i) * 4096);
#pragma unroll
    for (int i = 0; i < 8; i++) {
#pragma unroll
      for (int b = 0; b < Bq; b++) {
        float xv = xs[b][r + i];
        acc[b].x = fmaf(xv, w[i].x, acc[b].x);
        acc[b].y = fmaf(xv, w[i].y, acc[b].y);
        acc[b].z = fmaf(xv, w[i].z, acc[b].z);
        acc[b].w = fmaf(xv, w[i].w, acc[b].w);
      }
    }
  }
#pragma unroll
  for (int b = 0; b < Bq; b++)
    *(float4*)&part[((size_t)sp * Bq + b) * 4096 + cbase + 4 * tid] = acc[b];
}

// out[b][c] = sum_s part[s][b][c]. grid 128, block 256.
__global__ __launch_bounds__(256) void o_reduce(
    const float* __restrict__ part, float* __restrict__ out) {
  int idx = blockIdx.x * 256 + threadIdx.x;  // 0..32767
  int b = idx >> 12, c = idx & 4095;
  float v = 0.f;
#pragma unroll 8
  for (int s = 0; s < NSPLIT; s++) v += part[((size_t)s * Bq + b) * 4096 + c];
  out[idx] = v;
}

// Reduce QKV partials, then rmsnorm+rope. One wave per vector:
// 256 q -> qvec, 64 k -> key_cache[step], 64 v -> value_cache[step].
__global__ __launch_bounds__(256) void normrope(
    const float* __restrict__ part, const float* __restrict__ cosp,
    const float* __restrict__ sinp, const float* __restrict__ qnw,
    const float* __restrict__ knw, const int* __restrict__ step_ptr,
    float* __restrict__ kcache, float* __restrict__ vcache,
    float* __restrict__ qvec) {
  int tid = threadIdx.x;
  int lane = tid & 63, wid = tid >> 6;
  int vec = blockIdx.x * 4 + wid;  // 0..383
  int step = *step_ptr;
  int b, c0;
  const float* nw = 0;
  float* dst;
  bool donorm;
  if (vec < 256) {  // q heads
    b = vec >> 5;
    int h = vec & 31;
    c0 = h * HDq;
    nw = qnw; donorm = true;
    dst = qvec + b * (NHq * HDq) + h * HDq;
  } else if (vec < 320) {  // k heads
    int v = vec - 256;
    b = v >> 3;
    int kvh = v & 7;
    c0 = NHq * HDq + kvh * HDq;
    nw = knw; donorm = true;
    dst = kcache + (((size_t)(b * KVHq + kvh)) * Sq + step) * HDq;
  } else {  // v heads
    int v = vec - 320;
    b = v >> 3;
    int kvh = v & 7;
    c0 = (NHq + KVHq) * HDq + kvh * HDq;
    donorm = false;
    dst = vcache + (((size_t)(b * KVHq + kvh)) * Sq + step) * HDq;
  }
  float x0 = 0.f, x1 = 0.f;
#pragma unroll 8
  for (int s = 0; s < NSPLIT; s++) {
    const float* p = part + ((size_t)s * Bq + b) * QKV_N + c0;
    x0 += p[lane];
    x1 += p[lane + 64];
  }
  if (!donorm) {
    dst[lane] = x0;
    dst[lane + 64] = x1;
    return;
  }
  float ss = fmaf(x0, x0, x1 * x1);
#pragma unroll
  for (int off = 32; off; off >>= 1) ss += __shfl_xor(ss, off, 64);
  float sc = rsqrtf(ss * (1.0f / HDq) + 1e-6f);
  float n0 = x0 * sc * nw[lane], n1 = x1 * sc * nw[lane + 64];
  float c0v = cosp[b * HDq + lane], c1v = cosp[b * HDq + lane + 64];
  float s0v = sinp[b * HDq + lane], s1v = sinp[b * HDq + lane + 64];
  dst[lane] = fmaf(n0, c0v, -n1 * s0v);
  dst[lane + 64] = fmaf(n1, c1v, n0 * s1v);
}

// Flash-decode partial: grid (NCHUNK, B*KVH). 128 threads, 4 GQA heads x 128 positions.
// K loop staged 8 float4s deep (128B/thread in flight) -- fits in ~90 VGPRs, no spill.
__global__ __launch_bounds__(128, 3) void attn_partial(
    const float* __restrict__ qvec, const float* __restrict__ kc,
    const float* __restrict__ vc, const int* __restrict__ step_ptr,
    float* __restrict__ pm, float* __restrict__ pl, float* __restrict__ po) {
  int c = blockIdx.x;
  int bk = blockIdx.y;  // b*KVH + kvh
  int b = bk >> 3, kvh = bk & 7;
  int step = *step_ptr;
  int base = c * CHUNK;
  int pidx = (bk * NCHUNK + c) * 4;
  int tid = threadIdx.x;
  if (base > step) {
    if (tid < 4) { pm[pidx + tid] = -1e38f; pl[pidx + tid] = 0.0f; }
    return;
  }
  __shared__ float4 qs4[4][32];
  __shared__ float pls[4][CHUNK];
  __shared__ float redm[4][2];
  __shared__ float redl[4][2];
  {
    const float4* qv4 = (const float4*)(qvec + b * (NHq * HDq));
    qs4[tid >> 5][tid & 31] = qv4[(kvh * 4 + (tid >> 5)) * 32 + (tid & 31)];
  }
  __syncthreads();

  int s = base + tid;  // one position per thread
  const float4* krow4 = (const float4*)(kc + (((size_t)bk) * Sq + s) * HDq);
  float sc[4] = {0, 0, 0, 0};
  for (int d0 = 0; d0 < 32; d0 += 8) {
    float4 kk[8];
#pragma unroll
    for (int i = 0; i < 8; i++) kk[i] = krow4[d0 + i];
#pragma unroll
    for (int i = 0; i < 8; i++) {
#pragma unroll
      for (int g = 0; g < 4; g++) {
        float4 qq = qs4[g][d0 + i];
        sc[g] += kk[i].x * qq.x + kk[i].y * qq.y + kk[i].z * qq.z + kk[i].w * qq.w;
      }
    }
  }
  const float scaling = 0.08838834764831845f;  // 1/sqrt(128)
  bool valid = (s <= step);
#pragma unroll
  for (int g = 0; g < 4; g++) sc[g] = valid ? sc[g] * scaling : -1e30f;

  int lane = tid & 63, wid = tid >> 6;
#pragma unroll
  for (int g = 0; g < 4; g++) {
    float v = sc[g];
#pragma unroll
    for (int off = 32; off; off >>= 1) v = fmaxf(v, __shfl_xor(v, off, 64));
    if (lane == 0) redm[g][wid] = v;
  }
  __syncthreads();
  float m[4];
#pragma unroll
  for (int g = 0; g < 4; g++) m[g] = fmaxf(redm[g][0], redm[g][1]);
#pragma unroll
  for (int g = 0; g < 4; g++) {
    float p = __expf(sc[g] - m[g]);  // invalid lanes underflow to 0
    pls[g][tid] = p;
    float v = p;
#pragma unroll
    for (int off = 32; off; off >>= 1) v += __shfl_xor(v, off, 64);
    if (lane == 0) redl[g][wid] = v;
  }
  __syncthreads();
  if (tid < 4) {
    pm[pidx + tid] = m[tid];
    pl[pidx + tid] = redl[tid][0] + redl[tid][1];
  }
  // o_c[g][d] = sum_s p[g][s] * V[s][d]; thread = d; staged 8-deep
  const float* vbase = vc + (((size_t)bk) * Sq + base) * HDq + tid;
  float o0 = 0.f, o1 = 0.f, o2 = 0.f, o3 = 0.f;
  for (int ss = 0; ss < CHUNK; ss += 8) {
    float vv[8];
#pragma unroll
    for (int i = 0; i < 8; i++) vv[i] = vbase[(size_t)(ss + i) * HDq];
#pragma unroll
    for (int i = 0; i < 8; i++) {
      o0 = fmaf(pls[0][ss + i], vv[i], o0);
      o1 = fmaf(pls[1][ss + i], vv[i], o1);
      o2 = fmaf(pls[2][ss + i], vv[i], o2);
      o3 = fmaf(pls[3][ss + i], vv[i], o3);
    }
  }
  po[(size_t)(pidx + 0) * HDq + tid] = o0;
  po[(size_t)(pidx + 1) * HDq + tid] = o1;
  po[(size_t)(pidx + 2) * HDq + tid] = o2;
  po[(size_t)(pidx + 3) * HDq + tid] = o3;
}

__global__ __launch_bounds__(128) void attn_combine(
    const float* __restrict__ pm, const float* __restrict__ pl,
    const float* __restrict__ po, float* __restrict__ aout) {
  int bh = blockIdx.x;  // 0..255
  int b = bh >> 5, h = bh & 31;
  int kvh = h >> 2, g = h & 3;
  int d = threadIdx.x;
  int bk = b * KVHq + kvh;
  float mv[NCHUNK];
  float M = -1e38f;
#pragma unroll
  for (int c = 0; c < NCHUNK; c++) {
    mv[c] = pm[(bk * NCHUNK + c) * 4 + g];
    M = fmaxf(M, mv[c]);
  }
  float L = 0.0f, o = 0.0f;
#pragma unroll
  for (int c = 0; c < NCHUNK; c++) {
    if (mv[c] > -1e37f) {
      float w = __expf(mv[c] - M);
      L = fmaf(pl[(bk * NCHUNK + c) * 4 + g], w, L);
      o = fmaf(po[(size_t)((bk * NCHUNK + c) * 4 + g) * HDq + d], w, o);
    }
  }
  aout[b * (NHq * HDq) + h * HDq + d] = o / L;
}

extern "C" void kernel_launch(void* const* d_in, const int* in_sizes, int n_in,
                              void* d_out, int out_size, void* d_ws, size_t ws_size,
                              hipStream_t stream) {
  const float* hidden = (const float*)d_in[0];
  const float* cosp   = (const float*)d_in[1];
  const float* sinp   = (const float*)d_in[2];
  float* kcache       = (float*)d_in[3];
  float* vcache       = (float*)d_in[4];
  // d_in[5] causal_mask unused (mask == skip s > step; masked exp underflows to 0)
  const float* q_w    = (const float*)d_in[6];
  const float* k_w    = (const float*)d_in[7];
  const float* v_w    = (const float*)d_in[8];
  const float* o_w    = (const float*)d_in[9];
  const float* qnw    = (const float*)d_in[10];
  const float* knw    = (const float*)d_in[11];
  const int* step_ptr = (const int*)d_in[12];
  float* out = (float*)d_out;
  float* ws = (float*)d_ws;

  float* part = ws;                    // max(64*8*6144, 64*8*4096) = 3,145,728 floats
  float* qvec = ws + 3145728;          // 8*32*128 = 32768
  float* aout = qvec + 32768;          // 32768
  float* pm   = aout + 32768;          // 64*32*4 = 8192
  float* pl   = pm + 8192;             // 8192
  float* po   = pl + 8192;             // 64*32*4*128 = 1048576
  (void)in_sizes; (void)n_in; (void)ws_size; (void)out_size;

  qkv_gemv<<<dim3(6, NSPLIT), 256, 0, stream>>>(hidden, q_w, k_w, v_w, part);
  normrope<<<96, 256, 0, stream>>>(part, cosp, sinp, qnw, knw, step_ptr, kcache, vcache, qvec);
  attn_partial<<<dim3(NCHUNK, Bq * KVHq), 128, 0, stream>>>(qvec, kcache, vcache, step_ptr, pm, pl, po);
  attn_combine<<<Bq * NHq, 128, 0, stream>>>(pm, pl, po, aout);
  o_gemv<<<dim3(4, NSPLIT), 256, 0, stream>>>(aout, o_w, part);
  o_reduce<<<128, 256, 0, stream>>>(part, out);
}